// Round 4
// baseline (363.192 us; speedup 1.0000x reference)
//
#include <hip/hip_runtime.h>
#include <stdint.h>

#define CC 256
#define NN 4096   // H*W = 64*64

typedef __attribute__((ext_vector_type(8))) short short8;
typedef __attribute__((ext_vector_type(4))) float floatx4;
typedef __attribute__((ext_vector_type(4))) unsigned int uint4v;
typedef __attribute__((ext_vector_type(2))) unsigned int uint2v;

__device__ __forceinline__ unsigned short f2bf(float f) {
    unsigned int u = __builtin_bit_cast(unsigned int, f);
    u = (u + 0x7FFFu + ((u >> 16) & 1u)) >> 16;   // RNE
    return (unsigned short)u;
}

__device__ __forceinline__ floatx4 mfma16(short8 a, short8 b, floatx4 c) {
    return __builtin_amdgcn_mfma_f32_16x16x32_bf16(a, b, c, 0, 0, 0);
}

// ---------------------------------------------------------------------------
// Fragment layouts (16x16x32 bf16; A-frag == B-frag lane map:
//   element(row = 16*tile + (lane&15), k = 32*kk + (lane>>4)*8 + j)):
// xB[b][nt 256][kk 8][lane][j] : row = n (pixel), k = c   (S operands)
// xG[b][mt 64][cct 16][kk2 2][lane][j] : row = c, k = m   (G2 A-operand)
// wF[ct 16][kk 8][lane][j]     : row = out-c, k = in-c    (epilogue A)
// ---------------------------------------------------------------------------

// ---------------------------------------------------------------------------
// k_zero: out := 0 (k_fused halves accumulate via atomicAdd)
// ---------------------------------------------------------------------------
__global__ __launch_bounds__(256) void k_zero(float* __restrict__ out) {
    floatx4 z = {0.f, 0.f, 0.f, 0.f};
    size_t base = ((size_t)blockIdx.x * 256 + threadIdx.x) * 4;
    #pragma unroll
    for (int j = 0; j < 4; ++j)
        *(floatx4*)(out + base + (size_t)j * 1048576) = z;
}

// ---------------------------------------------------------------------------
// k_trans (verbatim): x -> xB + xG + partial norms psum.
// ---------------------------------------------------------------------------
__global__ __launch_bounds__(256) void k_trans(const float* __restrict__ x,
                                               unsigned short* __restrict__ xB,
                                               unsigned short* __restrict__ xG,
                                               float* __restrict__ psum) {
    int blk = blockIdx.x;
    int b  = blk >> 8;
    int cc = (blk >> 6) & 3;
    int nc = blk & 63;
    int c0 = cc << 6, n0 = nc << 6;
    __shared__ float tile[64][65];
    __shared__ float red[4][64];
    int t = threadIdx.x;
    {
        int c   = t >> 2;
        int nn4 = (t & 3) << 4;
        const float* src = x + (size_t)(b * CC + c0 + c) * NN + n0 + nn4;
        #pragma unroll
        for (int j = 0; j < 16; j += 4) {
            floatx4 v = *(const floatx4*)(src + j);
            tile[c][nn4 + j + 0] = v[0];
            tile[c][nn4 + j + 1] = v[1];
            tile[c][nn4 + j + 2] = v[2];
            tile[c][nn4 + j + 3] = v[3];
        }
    }
    __syncthreads();
    int g = t >> 6, lane = t & 63, l15 = lane & 15, q = lane >> 4;
    #pragma unroll
    for (int kkl = 0; kkl < 2; ++kkl) {
        unsigned int w[4];
        #pragma unroll
        for (int j = 0; j < 4; ++j) {
            unsigned int lo = f2bf(tile[32 * kkl + 8 * q + 2 * j][16 * g + l15]);
            unsigned int hi = f2bf(tile[32 * kkl + 8 * q + 2 * j + 1][16 * g + l15]);
            w[j] = lo | (hi << 16);
        }
        uint4v p = {w[0], w[1], w[2], w[3]};
        *(uint4v*)(xB + ((size_t)(b * 256 + (n0 >> 4) + g) * 8 + (c0 >> 5) + kkl) * 512
                   + lane * 8) = p;
    }
    #pragma unroll
    for (int kk2 = 0; kk2 < 2; ++kk2) {
        unsigned int w[4];
        #pragma unroll
        for (int j = 0; j < 4; ++j) {
            unsigned int lo = f2bf(tile[16 * g + l15][32 * kk2 + 8 * q + 2 * j]);
            unsigned int hi = f2bf(tile[16 * g + l15][32 * kk2 + 8 * q + 2 * j + 1]);
            w[j] = lo | (hi << 16);
        }
        uint4v p = {w[0], w[1], w[2], w[3]};
        *(uint4v*)(xG + (size_t)(b * 64 + nc) * 16 * 1024
                   + ((size_t)((c0 >> 4) + g)) * 1024 + kk2 * 512 + lane * 8) = p;
    }
    {
        int n  = t & 63;
        int cq = t >> 6;
        float ss = 0.f;
        #pragma unroll
        for (int i = 0; i < 16; ++i) {
            float v = tile[cq * 16 + i][n];
            ss = fmaf(v, v, ss);
        }
        red[cq][n] = ss;
    }
    __syncthreads();
    if (t < 64) {
        float s = red[0][t] + red[1][t] + red[2][t] + red[3][t];
        psum[((size_t)(b * 64 + nc) * 64 + t) * 4 + cc] = s;
    }
}

// ---------------------------------------------------------------------------
// k_invwcast (verbatim)
// ---------------------------------------------------------------------------
__global__ __launch_bounds__(256) void k_invwcast(const float* __restrict__ psum,
                                                  float* __restrict__ invn,
                                                  const float* __restrict__ Wm,
                                                  unsigned short* __restrict__ wF) {
    int bid = blockIdx.x;
    int t = threadIdx.x;
    if (bid < 64) {
        int i = bid * 256 + t;
        floatx4 p = *(const floatx4*)(psum + (size_t)i * 4);
        float ss = (p[0] + p[1]) + (p[2] + p[3]);
        invn[i] = 1.f / fmaxf(sqrtf(ss), 1e-8f);
    } else {
        int idx = (bid - 64) * 256 + t;          // 0..8191
        int f = idx >> 6, lane = idx & 63;
        int ct = f >> 3, kk = f & 7;
        int l15 = lane & 15, q = lane >> 4;
        const float* src = Wm + (size_t)(16 * ct + l15) * CC + 32 * kk + 8 * q;
        floatx4 a = *(const floatx4*)src;
        floatx4 c = *(const floatx4*)(src + 4);
        unsigned int w0 = f2bf(a[0]) | ((unsigned int)f2bf(a[1]) << 16);
        unsigned int w1 = f2bf(a[2]) | ((unsigned int)f2bf(a[3]) << 16);
        unsigned int w2 = f2bf(c[0]) | ((unsigned int)f2bf(c[1]) << 16);
        unsigned int w3 = f2bf(c[2]) | ((unsigned int)f2bf(c[3]) << 16);
        uint4v p = {w0, w1, w2, w3};
        *(uint4v*)(wF + (size_t)f * 512 + lane * 8) = p;
    }
}

// ---------------------------------------------------------------------------
// k_fused v12: v9 step structure VERBATIM (register bq double-buffer, xg/inv
// 1-step prefetch, pbuf parity, lgkmcnt(0)+barrier; no staging, no setprio).
// Change: key-axis split. 512 blocks x 512 thr; block h in {0,1} handles key
// tiles 32h..32h+31 (32 steps). Z and colsum are linear in the key sum, so
// each half runs the full W*Zh + b*sh epilogue and atomicAdds into the
// pre-zeroed output. VGPR<=128 via __launch_bounds__(512,4) -> 2 blocks/CU =
// 2 INDEPENDENT barrier domains (the v9 structure had zero independent waves
// to cover its per-step barrier drain; this is the isolated test of that
// theory). Batch-affine XCD swizzle kept (FETCH 69->17MB proved it).
// ---------------------------------------------------------------------------
#define FUSED_STEP(IT, BQC, BQN, XGP, XGC, INVP, INVC, DO_G2)                  \
    {                                                                          \
        /* issue next key tile */                                              \
        _Pragma("unroll")                                                      \
        for (int kk = 0; kk < 8; ++kk)                                         \
            BQN[kk] = *(const short8*)(bqp + kk * 512);                        \
        bqp += 16384;                                                          \
        /* xg for G2(IT) (consumed next step) + inv prefetch */                \
        _Pragma("unroll")                                                      \
        for (int ci = 0; ci < 2; ++ci)                                         \
            _Pragma("unroll")                                                  \
            for (int kk2 = 0; kk2 < 2; ++kk2)                                  \
                XGC[ci][kk2] = *(const short8*)(xgp + ci * 8192 + kk2 * 512);  \
        xgp += 16384;                                                          \
        INVC = *(const floatx4*)invmp;                                         \
        invmp += 64;                                                           \
        /* S(IT) transposed: A=keys, B=queries -> D rows = m-local */          \
        floatx4 s0a = zero4, s0b = zero4, s1a = zero4, s1b = zero4;            \
        _Pragma("unroll")                                                      \
        for (int kk = 0; kk < 8; kk += 2) {                                    \
            s0a = mfma16(BQC[kk],     aq[0][kk],     s0a);                     \
            s1a = mfma16(BQC[kk],     aq[1][kk],     s1a);                     \
            s0b = mfma16(BQC[kk + 1], aq[0][kk + 1], s0b);                     \
            s1b = mfma16(BQC[kk + 1], aq[1][kk + 1], s1b);                     \
        }                                                                      \
        /* G2(IT-1): pbuf[(IT-1)&1] x XGP (loaded at step IT-1) */             \
        if (DO_G2) {                                                           \
            const unsigned short* pbR = pbuf[((IT) - 1) & 1];                  \
            _Pragma("unroll")                                                  \
            for (int kk2 = 0; kk2 < 2; ++kk2)                                  \
                _Pragma("unroll")                                              \
                for (int nqs = 0; nqs < 4; ++nqs) {                            \
                    short8 pbf = *(const short8*)(pbR + (16 * nqs + l15) * 72  \
                                                  + kk2 * 32 + q * 8);         \
                    Zacc[0][nqs] = mfma16(XGP[0][kk2], pbf, Zacc[0][nqs]);     \
                    Zacc[1][nqs] = mfma16(XGP[1][kk2], pbf, Zacc[1][nqs]);     \
                }                                                              \
        }                                                                      \
        /* P(IT) = relu(S*inv)^2 -> packed b64 -> pbuf[IT&1]; csum */          \
        {                                                                      \
            unsigned short* pbW = pbuf[(IT) & 1];                              \
            _Pragma("unroll")                                                  \
            for (int s = 0; s < 2; ++s) {                                      \
                floatx4 sv = (s == 0) ? (s0a + s0b) : (s1a + s1b);             \
                unsigned int pk0, pk1;                                         \
                float v0 = sv[0] * (INVP[0] * invq[s]);                        \
                float v1 = sv[1] * (INVP[1] * invq[s]);                        \
                float v2 = sv[2] * (INVP[2] * invq[s]);                        \
                float v3 = sv[3] * (INVP[3] * invq[s]);                        \
                v0 = fmaxf(v0, 0.f); v1 = fmaxf(v1, 0.f);                      \
                v2 = fmaxf(v2, 0.f); v3 = fmaxf(v3, 0.f);                      \
                v0 *= v0; v1 *= v1; v2 *= v2; v3 *= v3;                        \
                csum[s] += (v0 + v1) + (v2 + v3);                              \
                pk0 = __byte_perm(__builtin_bit_cast(unsigned int, v0) + 0x8000u, \
                                  __builtin_bit_cast(unsigned int, v1) + 0x8000u, \
                                  0x7632);                                     \
                pk1 = __byte_perm(__builtin_bit_cast(unsigned int, v2) + 0x8000u, \
                                  __builtin_bit_cast(unsigned int, v3) + 0x8000u, \
                                  0x7632);                                     \
                uint2v w2 = {pk0, pk1};                                        \
                *(uint2v*)(pbW + (16 * (2 * np + s) + l15) * 72                \
                           + 16 * ms + 4 * q) = w2;                            \
            }                                                                  \
        }                                                                      \
        asm volatile("s_waitcnt lgkmcnt(0)\n\ts_barrier" ::: "memory");        \
    }

__global__ __launch_bounds__(512, 4) void k_fused(
        const unsigned short* __restrict__ xB,    // S frags
        const unsigned short* __restrict__ xG,    // G2 A frags
        const unsigned short* __restrict__ wF,    // W A-frags
        const float* __restrict__ bias,
        const float* __restrict__ invn,           // [B][N]
        float* __restrict__ out) {                // [B][C][N] f32 (atomicAdd)
    int blk = blockIdx.x;
    // batch-affine XCD swizzle: XCD (blk&7) hosts batch (blk&7)>>1 only;
    // bijective over 512: blk = 8*(r>>1) + 2*b + (r&1), r = qt*2 + h
    int b  = (blk & 7) >> 1;
    int r  = ((blk >> 3) << 1) | (blk & 1);       // 0..127
    int qt = r >> 1;                              // 0..63
    int h  = r & 1;                               // key half
    int n0 = qt << 6;                             // 64 queries per block
    int t  = threadIdx.x;
    int wv = t >> 6, lane = t & 63;
    int l15 = lane & 15, q = lane >> 4;
    int ms = wv & 3;
    int np = wv >> 2;                // nq pair {2np, 2np+1}

    __shared__ unsigned short pbuf[2][64 * 72];   // [parity][nq row][72 m]
    __shared__ unsigned short zbuf[64 * 264];     // epilogue Z
    __shared__ float spbuf2[4][64];               // colsum partials [ms][nq]

    const unsigned short* xBb = xB + (size_t)b * 256 * 8 * 512;
    const unsigned short* xGb = xG + (size_t)b * 64 * 16 * 1024;
    const float* invb = invn + b * NN;

    // persistent Xq frags (B operand of transposed S)
    short8 aq[2][8];
    #pragma unroll
    for (int s = 0; s < 2; ++s)
        #pragma unroll
        for (int kk = 0; kk < 8; ++kk)
            aq[s][kk] = *(const short8*)(xBb
                + ((size_t)((n0 >> 4) + 2 * np + s) * 8 + kk) * 512 + lane * 8);
    float invq[2];
    #pragma unroll
    for (int s = 0; s < 2; ++s) invq[s] = invb[n0 + 16 * (2 * np + s) + l15];

    floatx4 zero4 = {0.f, 0.f, 0.f, 0.f};
    floatx4 Zacc[2][4];              // [ci: cct=wv+8ci][nqs]
    #pragma unroll
    for (int ci = 0; ci < 2; ++ci)
        #pragma unroll
        for (int nqs = 0; nqs < 4; ++nqs) Zacc[ci][nqs] = zero4;
    float csum[2] = {0.f, 0.f};

    // hot-loop pointers; key half h => start at key tile 32h
    const unsigned short* bqp   = xBb + (size_t)h * 524288 + ms * 4096 + lane * 8;
    const unsigned short* xgp   = xGb + (size_t)h * 524288 + wv * 1024 + lane * 8;
    const float*          invmp = invb + h * 2048 + 16 * ms + 4 * q;

    short8 bqA[8], bqB[8];
    short8 xgA[2][2], xgB[2][2];
    floatx4 invA, invB;
    #pragma unroll
    for (int kk = 0; kk < 8; ++kk)
        bqA[kk] = *(const short8*)(bqp + kk * 512);
    bqp += 16384;
    invA = *(const floatx4*)invmp;
    invmp += 64;

    // peel it=0 (no G2 yet); loads xgA (mt-local 0), invB
    FUSED_STEP(0, bqA, bqB, xgB, xgA, invA, invB, false)
    // pairs it = 1..30
    for (int it2 = 0; it2 < 15; ++it2) {
        FUSED_STEP(2 * it2 + 1, bqB, bqA, xgA, xgB, invB, invA, true)
        FUSED_STEP(2 * it2 + 2, bqA, bqB, xgB, xgA, invA, invB, true)
    }
    // it = 31
    FUSED_STEP(31, bqB, bqA, xgA, xgB, invB, invA, true)
    // final G2(31): pbuf[1] x xgB (loaded at step 31, mt-local 31)
    {
        const unsigned short* pbR = pbuf[1];
        #pragma unroll
        for (int kk2 = 0; kk2 < 2; ++kk2)
            #pragma unroll
            for (int nqs = 0; nqs < 4; ++nqs) {
                short8 pbf = *(const short8*)(pbR + (16 * nqs + l15) * 72
                                              + kk2 * 32 + q * 8);
                Zacc[0][nqs] = mfma16(xgB[0][kk2], pbf, Zacc[0][nqs]);
                Zacc[1][nqs] = mfma16(xgB[1][kk2], pbf, Zacc[1][nqs]);
            }
    }

    // ---- colsum reduce over q-groups (lanes ^16, ^32) ----
    #pragma unroll
    for (int s = 0; s < 2; ++s) {
        csum[s] += __shfl_xor(csum[s], 16, 64);
        csum[s] += __shfl_xor(csum[s], 32, 64);
    }

    __syncthreads();
    // Z -> zbuf (scalar stores, dedicated LDS)
    #pragma unroll
    for (int ci = 0; ci < 2; ++ci) {
        int cct = wv + 8 * ci;
        #pragma unroll
        for (int nqs = 0; nqs < 4; ++nqs)
            #pragma unroll
            for (int i = 0; i < 4; ++i)
                zbuf[(16 * nqs + l15) * 264 + 16 * cct + 4 * q + i] = f2bf(Zacc[ci][nqs][i]);
    }
    if (q == 0) {
        #pragma unroll
        for (int s = 0; s < 2; ++s)
            spbuf2[ms][16 * (2 * np + s) + l15] = csum[s];
    }
    __syncthreads();

    float svals[4];
    #pragma unroll
    for (int nqs = 0; nqs < 4; ++nqs)
        svals[nqs] = spbuf2[0][16 * nqs + l15] + spbuf2[1][16 * nqs + l15]
                   + spbuf2[2][16 * nqs + l15] + spbuf2[3][16 * nqs + l15];

    // O_h = W*Z_h + b*s_h, accumulated into out via atomicAdd
    float* ob = out + (size_t)b * CC * NN;
    floatx4 oa[2][4];
    #pragma unroll
    for (int ci = 0; ci < 2; ++ci) {
        int ct = wv + 8 * ci;
        floatx4 bv = *(const floatx4*)(bias + 16 * ct + 4 * q);
        #pragma unroll
        for (int nqs = 0; nqs < 4; ++nqs)
            #pragma unroll
            for (int i = 0; i < 4; ++i) oa[ci][nqs][i] = bv[i] * svals[nqs];
    }
    #pragma unroll
    for (int kk = 0; kk < 8; ++kk) {
        short8 wf0 = *(const short8*)(wF + (size_t)(wv * 8 + kk) * 512 + lane * 8);
        short8 wf1 = *(const short8*)(wF + (size_t)((wv + 8) * 8 + kk) * 512 + lane * 8);
        #pragma unroll
        for (int nqs = 0; nqs < 4; ++nqs) {
            short8 zf = *(const short8*)(&zbuf[(16 * nqs + l15) * 264 + 32 * kk + 8 * q]);
            oa[0][nqs] = mfma16(wf0, zf, oa[0][nqs]);
            oa[1][nqs] = mfma16(wf1, zf, oa[1][nqs]);
        }
    }
    #pragma unroll
    for (int ci = 0; ci < 2; ++ci) {
        int ct = wv + 8 * ci;
        #pragma unroll
        for (int nqs = 0; nqs < 4; ++nqs)
            #pragma unroll
            for (int i = 0; i < 4; ++i)
                atomicAdd(&ob[(size_t)(16 * ct + 4 * q + i) * NN + n0 + 16 * nqs + l15],
                          oa[ci][nqs][i]);
    }
}

// ---------------------------------------------------------------------------
extern "C" void kernel_launch(void* const* d_in, const int* in_sizes, int n_in,
                              void* d_out, int out_size, void* d_ws, size_t ws_size,
                              hipStream_t stream) {
    const float* x    = (const float*)d_in[0];   // [4,256,64,64]
    const float* Wm   = (const float*)d_in[1];   // [256,256]
    const float* bias = (const float*)d_in[2];   // [256]
    float* out = (float*)d_out;

    // ws: psum 256KB | invn 64KB | xB 8MB | xG 8MB | wF 128KB  (~16.8MB)
    char* ws = (char*)d_ws;
    float* psum         = (float*)ws;
    float* invn         = (float*)(ws + 262144);
    unsigned short* xB  = (unsigned short*)(ws + 262144 + 65536);
    unsigned short* xG  = (unsigned short*)(ws + 262144 + 65536 + 8388608);
    unsigned short* wF  = (unsigned short*)(ws + 262144 + 65536 + 2 * 8388608);

    k_zero    <<<1024, 256, 0, stream>>>(out);
    k_trans   <<<1024, 256, 0, stream>>>(x, xB, xG, psum);
    k_invwcast<<<96,   256, 0, stream>>>(psum, invn, Wm, wF);
    k_fused   <<<512,  512, 0, stream>>>(xB, xG, wF, bias, invn, out);
}

// Round 7
// 185.959 us; speedup vs baseline: 1.9531x; 1.9531x over previous
//
#include <hip/hip_runtime.h>
#include <stdint.h>

#define CC 256
#define NN 4096   // H*W = 64*64

typedef __attribute__((ext_vector_type(8))) short short8;
typedef __attribute__((ext_vector_type(4))) float floatx4;
typedef __attribute__((ext_vector_type(4))) unsigned int uint4v;
typedef __attribute__((ext_vector_type(2))) unsigned int uint2v;

__device__ __forceinline__ unsigned short f2bf(float f) {
    unsigned int u = __builtin_bit_cast(unsigned int, f);
    u = (u + 0x7FFFu + ((u >> 16) & 1u)) >> 16;   // RNE
    return (unsigned short)u;
}

__device__ __forceinline__ floatx4 mfma16(short8 a, short8 b, floatx4 c) {
    return __builtin_amdgcn_mfma_f32_16x16x32_bf16(a, b, c, 0, 0, 0);
}

// ---------------------------------------------------------------------------
// Fragment layouts (16x16x32 bf16; A-frag == B-frag lane map:
//   element(row = 16*tile + (lane&15), k = 32*kk + (lane>>4)*8 + j)):
// xB[b][nt 256][kk 8][lane][j] : row = n (pixel), k = c   (S operands)
// xG[b][mt 64][cct 16][kk2 2][lane][j] : row = c, k = m   (G2 A-operand)
// wF[ct 16][kk 8][lane][j]     : row = out-c, k = in-c    (epilogue A)
// ---------------------------------------------------------------------------

// ---------------------------------------------------------------------------
// k_trans (v9 verbatim): x -> xB + xG + partial norms psum.
// ---------------------------------------------------------------------------
__global__ __launch_bounds__(256) void k_trans(const float* __restrict__ x,
                                               unsigned short* __restrict__ xB,
                                               unsigned short* __restrict__ xG,
                                               float* __restrict__ psum) {
    int blk = blockIdx.x;
    int b  = blk >> 8;
    int cc = (blk >> 6) & 3;
    int nc = blk & 63;
    int c0 = cc << 6, n0 = nc << 6;
    __shared__ float tile[64][65];
    __shared__ float red[4][64];
    int t = threadIdx.x;
    {
        int c   = t >> 2;
        int nn4 = (t & 3) << 4;
        const float* src = x + (size_t)(b * CC + c0 + c) * NN + n0 + nn4;
        #pragma unroll
        for (int j = 0; j < 16; j += 4) {
            floatx4 v = *(const floatx4*)(src + j);
            tile[c][nn4 + j + 0] = v[0];
            tile[c][nn4 + j + 1] = v[1];
            tile[c][nn4 + j + 2] = v[2];
            tile[c][nn4 + j + 3] = v[3];
        }
    }
    __syncthreads();
    int g = t >> 6, lane = t & 63, l15 = lane & 15, q = lane >> 4;
    #pragma unroll
    for (int kkl = 0; kkl < 2; ++kkl) {
        unsigned int w[4];
        #pragma unroll
        for (int j = 0; j < 4; ++j) {
            unsigned int lo = f2bf(tile[32 * kkl + 8 * q + 2 * j][16 * g + l15]);
            unsigned int hi = f2bf(tile[32 * kkl + 8 * q + 2 * j + 1][16 * g + l15]);
            w[j] = lo | (hi << 16);
        }
        uint4v p = {w[0], w[1], w[2], w[3]};
        *(uint4v*)(xB + ((size_t)(b * 256 + (n0 >> 4) + g) * 8 + (c0 >> 5) + kkl) * 512
                   + lane * 8) = p;
    }
    #pragma unroll
    for (int kk2 = 0; kk2 < 2; ++kk2) {
        unsigned int w[4];
        #pragma unroll
        for (int j = 0; j < 4; ++j) {
            unsigned int lo = f2bf(tile[16 * g + l15][32 * kk2 + 8 * q + 2 * j]);
            unsigned int hi = f2bf(tile[16 * g + l15][32 * kk2 + 8 * q + 2 * j + 1]);
            w[j] = lo | (hi << 16);
        }
        uint4v p = {w[0], w[1], w[2], w[3]};
        *(uint4v*)(xG + (size_t)(b * 64 + nc) * 16 * 1024
                   + ((size_t)((c0 >> 4) + g)) * 1024 + kk2 * 512 + lane * 8) = p;
    }
    {
        int n  = t & 63;
        int cq = t >> 6;
        float ss = 0.f;
        #pragma unroll
        for (int i = 0; i < 16; ++i) {
            float v = tile[cq * 16 + i][n];
            ss = fmaf(v, v, ss);
        }
        red[cq][n] = ss;
    }
    __syncthreads();
    if (t < 64) {
        float s = red[0][t] + red[1][t] + red[2][t] + red[3][t];
        psum[((size_t)(b * 64 + nc) * 64 + t) * 4 + cc] = s;
    }
}

// ---------------------------------------------------------------------------
// k_invwcast (verbatim)
// ---------------------------------------------------------------------------
__global__ __launch_bounds__(256) void k_invwcast(const float* __restrict__ psum,
                                                  float* __restrict__ invn,
                                                  const float* __restrict__ Wm,
                                                  unsigned short* __restrict__ wF) {
    int bid = blockIdx.x;
    int t = threadIdx.x;
    if (bid < 64) {
        int i = bid * 256 + t;
        floatx4 p = *(const floatx4*)(psum + (size_t)i * 4);
        float ss = (p[0] + p[1]) + (p[2] + p[3]);
        invn[i] = 1.f / fmaxf(sqrtf(ss), 1e-8f);
    } else {
        int idx = (bid - 64) * 256 + t;          // 0..8191
        int f = idx >> 6, lane = idx & 63;
        int ct = f >> 3, kk = f & 7;
        int l15 = lane & 15, q = lane >> 4;
        const float* src = Wm + (size_t)(16 * ct + l15) * CC + 32 * kk + 8 * q;
        floatx4 a = *(const floatx4*)src;
        floatx4 c = *(const floatx4*)(src + 4);
        unsigned int w0 = f2bf(a[0]) | ((unsigned int)f2bf(a[1]) << 16);
        unsigned int w1 = f2bf(a[2]) | ((unsigned int)f2bf(a[3]) << 16);
        unsigned int w2 = f2bf(c[0]) | ((unsigned int)f2bf(c[1]) << 16);
        unsigned int w3 = f2bf(c[2]) | ((unsigned int)f2bf(c[3]) << 16);
        uint4v p = {w0, w1, w2, w3};
        *(uint4v*)(wF + (size_t)f * 512 + lane * 8) = p;
    }
}

// ---------------------------------------------------------------------------
// k_fused v14: v9 frame + layouts VERBATIM, but TWO key tiles per macro-step
// with ONE barrier (pbuf[2 sets][2 eo]; macro T writes set T&1, G2 reads set
// (T-1)&1) -> 32 barriers instead of 64. xg prefetched one macro ahead
// (double-buffered pair-sets xgA/xgB). s_setprio(1) around MFMA clusters.
// SUBSTEP(EO): [G2(2(T-1)+EO) from pbuf[1-SETW][EO] x XGP[EO]] ->
// [S(2T+EO)] -> [P -> pbuf[SETW][EO]] -> [reload bq(2(T+1)+EO) in place].
// ---------------------------------------------------------------------------
#define SUBSTEP(SETW, EO, BQ, XGP, INV, DO_G2)                                 \
    {                                                                          \
        __builtin_amdgcn_s_setprio(1);                                         \
        if (DO_G2) {                                                           \
            const unsigned short* pbR = pbuf[1 - (SETW)][EO];                  \
            _Pragma("unroll")                                                  \
            for (int kk2 = 0; kk2 < 2; ++kk2)                                  \
                _Pragma("unroll")                                              \
                for (int nqs = 0; nqs < 4; ++nqs) {                            \
                    short8 pbf = *(const short8*)(pbR + (16 * nqs + l15) * 72  \
                                                  + kk2 * 32 + q * 8);         \
                    Zacc[0][nqs] = mfma16(XGP[EO][0][kk2], pbf, Zacc[0][nqs]); \
                    Zacc[1][nqs] = mfma16(XGP[EO][1][kk2], pbf, Zacc[1][nqs]); \
                }                                                              \
        }                                                                      \
        floatx4 s0a = zero4, s0b = zero4, s1a = zero4, s1b = zero4;            \
        _Pragma("unroll")                                                      \
        for (int kk = 0; kk < 8; kk += 2) {                                    \
            s0a = mfma16(BQ[kk],     aq[0][kk],     s0a);                      \
            s1a = mfma16(BQ[kk],     aq[1][kk],     s1a);                      \
            s0b = mfma16(BQ[kk + 1], aq[0][kk + 1], s0b);                      \
            s1b = mfma16(BQ[kk + 1], aq[1][kk + 1], s1b);                      \
        }                                                                      \
        __builtin_amdgcn_s_setprio(0);                                         \
        {                                                                      \
            unsigned short* pbW = pbuf[SETW][EO];                              \
            _Pragma("unroll")                                                  \
            for (int s = 0; s < 2; ++s) {                                      \
                floatx4 sv = (s == 0) ? (s0a + s0b) : (s1a + s1b);             \
                unsigned int pk0, pk1;                                         \
                float v0 = sv[0] * (INV[0] * invq[s]);                         \
                float v1 = sv[1] * (INV[1] * invq[s]);                         \
                float v2 = sv[2] * (INV[2] * invq[s]);                         \
                float v3 = sv[3] * (INV[3] * invq[s]);                         \
                v0 = fmaxf(v0, 0.f); v1 = fmaxf(v1, 0.f);                      \
                v2 = fmaxf(v2, 0.f); v3 = fmaxf(v3, 0.f);                      \
                v0 *= v0; v1 *= v1; v2 *= v2; v3 *= v3;                        \
                csum[s] += (v0 + v1) + (v2 + v3);                              \
                pk0 = __byte_perm(__builtin_bit_cast(unsigned int, v0) + 0x8000u, \
                                  __builtin_bit_cast(unsigned int, v1) + 0x8000u, \
                                  0x7632);                                     \
                pk1 = __byte_perm(__builtin_bit_cast(unsigned int, v2) + 0x8000u, \
                                  __builtin_bit_cast(unsigned int, v3) + 0x8000u, \
                                  0x7632);                                     \
                uint2v w2 = {pk0, pk1};                                        \
                *(uint2v*)(pbW + (16 * (2 * np + s) + l15) * 72                \
                           + 16 * ms + 4 * q) = w2;                            \
            }                                                                  \
        }                                                                      \
        _Pragma("unroll")                                                      \
        for (int kk = 0; kk < 8; ++kk)                                         \
            BQ[kk] = *(const short8*)(bqp + kk * 512);                         \
        bqp += 16384;                                                          \
    }

#define STEP2(SETW, XGP, XGC, DO_G2)                                           \
    {                                                                          \
        /* issue xg pair for tiles (2T, 2T+1), consumed NEXT macro */          \
        _Pragma("unroll")                                                      \
        for (int eo = 0; eo < 2; ++eo)                                         \
            _Pragma("unroll")                                                  \
            for (int ci = 0; ci < 2; ++ci)                                     \
                _Pragma("unroll")                                              \
                for (int kk2 = 0; kk2 < 2; ++kk2)                              \
                    XGC[eo][ci][kk2] = *(const short8*)(xgp + eo * 16384       \
                                                       + ci * 8192 + kk2 * 512); \
        xgp += 32768;                                                          \
        floatx4 invE = *(const floatx4*)invmp;                                 \
        floatx4 invO = *(const floatx4*)(invmp + 64);                          \
        invmp += 128;                                                          \
        SUBSTEP(SETW, 0, bqE, XGP, invE, DO_G2)                                \
        SUBSTEP(SETW, 1, bqO, XGP, invO, DO_G2)                                \
        asm volatile("s_waitcnt lgkmcnt(0)\n\ts_barrier" ::: "memory");        \
    }

__global__ __launch_bounds__(512, 1) void k_fused(
        const unsigned short* __restrict__ xB,    // S frags
        const unsigned short* __restrict__ xG,    // G2 A frags
        const unsigned short* __restrict__ wF,    // W A-frags
        const float* __restrict__ bias,
        const float* __restrict__ invn,           // [B][N]
        float* __restrict__ out) {                // [B][C][N] f32
    int blk = blockIdx.x;
    // batch-affine XCD swizzle: XCD (blk&7) hosts batch (blk&7)>>1 only;
    // bijective over 256: blk = 8*(qt>>1) + 2*b + (qt&1)
    int b  = (blk & 7) >> 1;
    int qt = ((blk >> 3) << 1) | (blk & 1);       // 0..63
    int n0 = qt << 6;                             // 64 queries per block
    int t  = threadIdx.x;
    int wv = t >> 6, lane = t & 63;
    int l15 = lane & 15, q = lane >> 4;
    int ms = wv & 3;
    int np = wv >> 2;                // nq pair {2np, 2np+1}

    __shared__ unsigned short pbuf[2][2][64 * 72]; // [set][eo][nq row][72 m]
    __shared__ unsigned short zbuf[64 * 264];      // epilogue Z
    __shared__ float spbuf2[4][64];                // colsum partials [ms][nq]

    const unsigned short* xBb = xB + (size_t)b * 256 * 8 * 512;
    const unsigned short* xGb = xG + (size_t)b * 64 * 16 * 1024;
    const float* invb = invn + b * NN;

    // persistent Xq frags (B operand of transposed S)
    short8 aq[2][8];
    #pragma unroll
    for (int s = 0; s < 2; ++s)
        #pragma unroll
        for (int kk = 0; kk < 8; ++kk)
            aq[s][kk] = *(const short8*)(xBb
                + ((size_t)((n0 >> 4) + 2 * np + s) * 8 + kk) * 512 + lane * 8);
    float invq[2];
    #pragma unroll
    for (int s = 0; s < 2; ++s) invq[s] = invb[n0 + 16 * (2 * np + s) + l15];

    floatx4 zero4 = {0.f, 0.f, 0.f, 0.f};
    floatx4 Zacc[2][4];              // [ci: cct=wv+8ci][nqs]
    #pragma unroll
    for (int ci = 0; ci < 2; ++ci)
        #pragma unroll
        for (int nqs = 0; nqs < 4; ++nqs) Zacc[ci][nqs] = zero4;
    float csum[2] = {0.f, 0.f};

    // hot-loop pointers (constant strides)
    const unsigned short* bqp   = xBb + ms * 4096 + lane * 8;      // tile 0
    const unsigned short* xgp   = xGb + wv * 1024 + lane * 8;      // mt 0
    const float*          invmp = invb + 16 * ms + 4 * q;          // m-tile 0

    short8 bqE[8], bqO[8];
    short8 xgA[2][2][2], xgB[2][2][2];   // [eo][ci][kk2]
    #pragma unroll
    for (int kk = 0; kk < 8; ++kk)
        bqE[kk] = *(const short8*)(bqp + kk * 512);
    bqp += 16384;
    #pragma unroll
    for (int kk = 0; kk < 8; ++kk)
        bqO[kk] = *(const short8*)(bqp + kk * 512);
    bqp += 16384;

    // macro T=0 (tiles 0,1; no G2 yet); loads xgA <- tiles 0,1
    STEP2(0, xgB, xgA, false)
    // macro T = 1..30
    for (int t2 = 0; t2 < 15; ++t2) {
        STEP2(1, xgA, xgB, true)      // T odd:  writes set1, reads set0
        STEP2(0, xgB, xgA, true)      // T even: writes set0, reads set1
    }
    // macro T = 31 (tiles 62,63); XGP=xgA (tiles 60,61), loads xgB <- 62,63
    STEP2(1, xgA, xgB, true)
    // final G2(62), G2(63): pbuf[1][eo] x xgB[eo]
    #pragma unroll
    for (int eo = 0; eo < 2; ++eo) {
        const unsigned short* pbR = pbuf[1][eo];
        #pragma unroll
        for (int kk2 = 0; kk2 < 2; ++kk2)
            #pragma unroll
            for (int nqs = 0; nqs < 4; ++nqs) {
                short8 pbf = *(const short8*)(pbR + (16 * nqs + l15) * 72
                                              + kk2 * 32 + q * 8);
                Zacc[0][nqs] = mfma16(xgB[eo][0][kk2], pbf, Zacc[0][nqs]);
                Zacc[1][nqs] = mfma16(xgB[eo][1][kk2], pbf, Zacc[1][nqs]);
            }
    }

    // ---- colsum reduce over q-groups (lanes ^16, ^32) ----
    #pragma unroll
    for (int s = 0; s < 2; ++s) {
        csum[s] += __shfl_xor(csum[s], 16, 64);
        csum[s] += __shfl_xor(csum[s], 32, 64);
    }

    __syncthreads();
    // Z -> zbuf (scalar stores, dedicated LDS)
    #pragma unroll
    for (int ci = 0; ci < 2; ++ci) {
        int cct = wv + 8 * ci;
        #pragma unroll
        for (int nqs = 0; nqs < 4; ++nqs)
            #pragma unroll
            for (int i = 0; i < 4; ++i)
                zbuf[(16 * nqs + l15) * 264 + 16 * cct + 4 * q + i] = f2bf(Zacc[ci][nqs][i]);
    }
    if (q == 0) {
        #pragma unroll
        for (int s = 0; s < 2; ++s)
            spbuf2[ms][16 * (2 * np + s) + l15] = csum[s];
    }
    __syncthreads();

    float svals[4];
    #pragma unroll
    for (int nqs = 0; nqs < 4; ++nqs)
        svals[nqs] = spbuf2[0][16 * nqs + l15] + spbuf2[1][16 * nqs + l15]
                   + spbuf2[2][16 * nqs + l15] + spbuf2[3][16 * nqs + l15];

    // O = W*Z + b*svals
    float* ob = out + (size_t)b * CC * NN;
    floatx4 oa[2][4];
    #pragma unroll
    for (int ci = 0; ci < 2; ++ci) {
        int ct = wv + 8 * ci;
        floatx4 bv = *(const floatx4*)(bias + 16 * ct + 4 * q);
        #pragma unroll
        for (int nqs = 0; nqs < 4; ++nqs)
            #pragma unroll
            for (int i = 0; i < 4; ++i) oa[ci][nqs][i] = bv[i] * svals[nqs];
    }
    #pragma unroll
    for (int kk = 0; kk < 8; ++kk) {
        short8 wf0 = *(const short8*)(wF + (size_t)(wv * 8 + kk) * 512 + lane * 8);
        short8 wf1 = *(const short8*)(wF + (size_t)((wv + 8) * 8 + kk) * 512 + lane * 8);
        #pragma unroll
        for (int nqs = 0; nqs < 4; ++nqs) {
            short8 zf = *(const short8*)(&zbuf[(16 * nqs + l15) * 264 + 32 * kk + 8 * q]);
            oa[0][nqs] = mfma16(wf0, zf, oa[0][nqs]);
            oa[1][nqs] = mfma16(wf1, zf, oa[1][nqs]);
        }
    }
    #pragma unroll
    for (int ci = 0; ci < 2; ++ci) {
        int ct = wv + 8 * ci;
        #pragma unroll
        for (int nqs = 0; nqs < 4; ++nqs)
            #pragma unroll
            for (int i = 0; i < 4; ++i)
                ob[(size_t)(16 * ct + 4 * q + i) * NN + n0 + 16 * nqs + l15] = oa[ci][nqs][i];
    }
}

// ---------------------------------------------------------------------------
extern "C" void kernel_launch(void* const* d_in, const int* in_sizes, int n_in,
                              void* d_out, int out_size, void* d_ws, size_t ws_size,
                              hipStream_t stream) {
    const float* x    = (const float*)d_in[0];   // [4,256,64,64]
    const float* Wm   = (const float*)d_in[1];   // [256,256]
    const float* bias = (const float*)d_in[2];   // [256]
    float* out = (float*)d_out;

    // ws: psum 256KB | invn 64KB | xB 8MB | xG 8MB | wF 128KB  (~16.8MB)
    char* ws = (char*)d_ws;
    float* psum         = (float*)ws;
    float* invn         = (float*)(ws + 262144);
    unsigned short* xB  = (unsigned short*)(ws + 262144 + 65536);
    unsigned short* xG  = (unsigned short*)(ws + 262144 + 65536 + 8388608);
    unsigned short* wF  = (unsigned short*)(ws + 262144 + 65536 + 2 * 8388608);

    k_trans   <<<1024, 256, 0, stream>>>(x, xB, xG, psum);
    k_invwcast<<<96,   256, 0, stream>>>(psum, invn, Wm, wF);
    k_fused   <<<256,  512, 0, stream>>>(xB, xG, wF, bias, invn, out);
}

// Round 8
// 164.339 us; speedup vs baseline: 2.2100x; 1.1316x over previous
//
#include <hip/hip_runtime.h>
#include <stdint.h>

#define CC 256
#define NN 4096   // H*W = 64*64

typedef __attribute__((ext_vector_type(8))) short short8;
typedef __attribute__((ext_vector_type(4))) float floatx4;
typedef __attribute__((ext_vector_type(4))) unsigned int uint4v;
typedef __attribute__((ext_vector_type(2))) unsigned int uint2v;

__device__ __forceinline__ unsigned short f2bf(float f) {
    unsigned int u = __builtin_bit_cast(unsigned int, f);
    u = (u + 0x7FFFu + ((u >> 16) & 1u)) >> 16;   // RNE
    return (unsigned short)u;
}

__device__ __forceinline__ floatx4 mfma16(short8 a, short8 b, floatx4 c) {
    return __builtin_amdgcn_mfma_f32_16x16x32_bf16(a, b, c, 0, 0, 0);
}

// ---------------------------------------------------------------------------
// Fragment layouts (16x16x32 bf16; A-frag == B-frag lane map:
//   element(row = 16*tile + (lane&15), k = 32*kk + (lane>>4)*8 + j)):
// xB[b][nt 256][kk 8][lane][j] : row = n (pixel), k = c   (S operands)
// xG[b][mt 64][cct 16][kk2 2][lane][j] : row = c, k = m   (G2 A-operand)
// wF[ct 16][kk 8][lane][j]     : row = out-c, k = in-c    (epilogue A)
// ---------------------------------------------------------------------------

// ---------------------------------------------------------------------------
// k_trans (round-0 verbatim): x -> xB + xG + partial norms psum.
// ---------------------------------------------------------------------------
__global__ __launch_bounds__(256) void k_trans(const float* __restrict__ x,
                                               unsigned short* __restrict__ xB,
                                               unsigned short* __restrict__ xG,
                                               float* __restrict__ psum) {
    int blk = blockIdx.x;
    int b  = blk >> 8;
    int cc = (blk >> 6) & 3;
    int nc = blk & 63;
    int c0 = cc << 6, n0 = nc << 6;
    __shared__ float tile[64][65];
    __shared__ float red[4][64];
    int t = threadIdx.x;
    {
        int c   = t >> 2;
        int nn4 = (t & 3) << 4;
        const float* src = x + (size_t)(b * CC + c0 + c) * NN + n0 + nn4;
        #pragma unroll
        for (int j = 0; j < 16; j += 4) {
            floatx4 v = *(const floatx4*)(src + j);
            tile[c][nn4 + j + 0] = v[0];
            tile[c][nn4 + j + 1] = v[1];
            tile[c][nn4 + j + 2] = v[2];
            tile[c][nn4 + j + 3] = v[3];
        }
    }
    __syncthreads();
    int g = t >> 6, lane = t & 63, l15 = lane & 15, q = lane >> 4;
    #pragma unroll
    for (int kkl = 0; kkl < 2; ++kkl) {
        unsigned int w[4];
        #pragma unroll
        for (int j = 0; j < 4; ++j) {
            unsigned int lo = f2bf(tile[32 * kkl + 8 * q + 2 * j][16 * g + l15]);
            unsigned int hi = f2bf(tile[32 * kkl + 8 * q + 2 * j + 1][16 * g + l15]);
            w[j] = lo | (hi << 16);
        }
        uint4v p = {w[0], w[1], w[2], w[3]};
        *(uint4v*)(xB + ((size_t)(b * 256 + (n0 >> 4) + g) * 8 + (c0 >> 5) + kkl) * 512
                   + lane * 8) = p;
    }
    #pragma unroll
    for (int kk2 = 0; kk2 < 2; ++kk2) {
        unsigned int w[4];
        #pragma unroll
        for (int j = 0; j < 4; ++j) {
            unsigned int lo = f2bf(tile[16 * g + l15][32 * kk2 + 8 * q + 2 * j]);
            unsigned int hi = f2bf(tile[16 * g + l15][32 * kk2 + 8 * q + 2 * j + 1]);
            w[j] = lo | (hi << 16);
        }
        uint4v p = {w[0], w[1], w[2], w[3]};
        *(uint4v*)(xG + (size_t)(b * 64 + nc) * 16 * 1024
                   + ((size_t)((c0 >> 4) + g)) * 1024 + kk2 * 512 + lane * 8) = p;
    }
    {
        int n  = t & 63;
        int cq = t >> 6;
        float ss = 0.f;
        #pragma unroll
        for (int i = 0; i < 16; ++i) {
            float v = tile[cq * 16 + i][n];
            ss = fmaf(v, v, ss);
        }
        red[cq][n] = ss;
    }
    __syncthreads();
    if (t < 64) {
        float s = red[0][t] + red[1][t] + red[2][t] + red[3][t];
        psum[((size_t)(b * 64 + nc) * 64 + t) * 4 + cc] = s;
    }
}

// ---------------------------------------------------------------------------
// k_invwcast (round-0 verbatim)
// ---------------------------------------------------------------------------
__global__ __launch_bounds__(256) void k_invwcast(const float* __restrict__ psum,
                                                  float* __restrict__ invn,
                                                  const float* __restrict__ Wm,
                                                  unsigned short* __restrict__ wF) {
    int bid = blockIdx.x;
    int t = threadIdx.x;
    if (bid < 64) {
        int i = bid * 256 + t;
        floatx4 p = *(const floatx4*)(psum + (size_t)i * 4);
        float ss = (p[0] + p[1]) + (p[2] + p[3]);
        invn[i] = 1.f / fmaxf(sqrtf(ss), 1e-8f);
    } else {
        int idx = (bid - 64) * 256 + t;          // 0..8191
        int f = idx >> 6, lane = idx & 63;
        int ct = f >> 3, kk = f & 7;
        int l15 = lane & 15, q = lane >> 4;
        const float* src = Wm + (size_t)(16 * ct + l15) * CC + 32 * kk + 8 * q;
        floatx4 a = *(const floatx4*)src;
        floatx4 c = *(const floatx4*)(src + 4);
        unsigned int w0 = f2bf(a[0]) | ((unsigned int)f2bf(a[1]) << 16);
        unsigned int w1 = f2bf(a[2]) | ((unsigned int)f2bf(a[3]) << 16);
        unsigned int w2 = f2bf(c[0]) | ((unsigned int)f2bf(c[1]) << 16);
        unsigned int w3 = f2bf(c[2]) | ((unsigned int)f2bf(c[3]) << 16);
        uint4v p = {w0, w1, w2, w3};
        *(uint4v*)(wF + (size_t)f * 512 + lane * 8) = p;
    }
}

// ---------------------------------------------------------------------------
// k_fused v15: round-0 v9 frame/layouts/registers VERBATIM (94.7us proven,
// VGPR 112), plus three register-neutral tweaks:
//  (1) batch-affine XCD swizzle (proven FETCH 69.5->17MB; working set/XCD =
//      4MB = L2 size),
//  (2) S-MFMAs issued BEFORE G2 so the 16 register-only S-MFMAs cover the
//      ~120cy latency of G2's pbuf ds_reads at the step head,
//  (3) s_setprio(1) around the MFMA cluster.
// ---------------------------------------------------------------------------
#define FUSED_STEP(IT, BQC, BQN, XGP, XGC, DO_G2)                              \
    {                                                                          \
        /* issue next key tile + this step's xg (consumed next step) */        \
        _Pragma("unroll")                                                      \
        for (int kk = 0; kk < 8; ++kk)                                         \
            BQN[kk] = *(const short8*)(bqp + kk * 512);                        \
        bqp += 16384;                                                          \
        _Pragma("unroll")                                                      \
        for (int ci = 0; ci < 2; ++ci)                                         \
            _Pragma("unroll")                                                  \
            for (int kk2 = 0; kk2 < 2; ++kk2)                                  \
                XGC[ci][kk2] = *(const short8*)(xgp + ci * 8192 + kk2 * 512);  \
        xgp += 16384;                                                          \
        floatx4 invm4 = *(const floatx4*)invmp;                                \
        invmp += 64;                                                           \
        __builtin_amdgcn_s_setprio(1);                                         \
        /* S(IT) transposed: A=keys, B=queries -> D rows = m-local */          \
        floatx4 s0a = zero4, s0b = zero4, s1a = zero4, s1b = zero4;            \
        _Pragma("unroll")                                                      \
        for (int kk = 0; kk < 8; kk += 2) {                                    \
            s0a = mfma16(BQC[kk],     aq[0][kk],     s0a);                     \
            s1a = mfma16(BQC[kk],     aq[1][kk],     s1a);                     \
            s0b = mfma16(BQC[kk + 1], aq[0][kk + 1], s0b);                     \
            s1b = mfma16(BQC[kk + 1], aq[1][kk + 1], s1b);                     \
        }                                                                      \
        /* G2(IT-1): pbuf[(IT-1)&1] x prev xg */                               \
        if (DO_G2) {                                                           \
            const unsigned short* pbR = pbuf[((IT) - 1) & 1];                  \
            _Pragma("unroll")                                                  \
            for (int kk2 = 0; kk2 < 2; ++kk2)                                  \
                _Pragma("unroll")                                              \
                for (int nqs = 0; nqs < 4; ++nqs) {                            \
                    short8 pbf = *(const short8*)(pbR + (16 * nqs + l15) * 72  \
                                                  + kk2 * 32 + q * 8);         \
                    Zacc[0][nqs] = mfma16(XGP[0][kk2], pbf, Zacc[0][nqs]);     \
                    Zacc[1][nqs] = mfma16(XGP[1][kk2], pbf, Zacc[1][nqs]);     \
                }                                                              \
        }                                                                      \
        __builtin_amdgcn_s_setprio(0);                                         \
        /* P(IT) = relu(S*inv)^2 -> packed b64 -> pbuf[IT&1]; csum */          \
        {                                                                      \
            unsigned short* pbW = pbuf[(IT) & 1];                              \
            _Pragma("unroll")                                                  \
            for (int s = 0; s < 2; ++s) {                                      \
                floatx4 sv = (s == 0) ? (s0a + s0b) : (s1a + s1b);             \
                unsigned int pk0, pk1;                                         \
                float v0 = sv[0] * (invm4[0] * invq[s]);                       \
                float v1 = sv[1] * (invm4[1] * invq[s]);                       \
                float v2 = sv[2] * (invm4[2] * invq[s]);                       \
                float v3 = sv[3] * (invm4[3] * invq[s]);                       \
                v0 = fmaxf(v0, 0.f); v1 = fmaxf(v1, 0.f);                      \
                v2 = fmaxf(v2, 0.f); v3 = fmaxf(v3, 0.f);                      \
                v0 *= v0; v1 *= v1; v2 *= v2; v3 *= v3;                        \
                csum[s] += (v0 + v1) + (v2 + v3);                              \
                pk0 = __byte_perm(__builtin_bit_cast(unsigned int, v0) + 0x8000u, \
                                  __builtin_bit_cast(unsigned int, v1) + 0x8000u, \
                                  0x7632);                                     \
                pk1 = __byte_perm(__builtin_bit_cast(unsigned int, v2) + 0x8000u, \
                                  __builtin_bit_cast(unsigned int, v3) + 0x8000u, \
                                  0x7632);                                     \
                uint2v w2 = {pk0, pk1};                                        \
                *(uint2v*)(pbW + (16 * (2 * np + s) + l15) * 72                \
                           + 16 * ms + 4 * q) = w2;                            \
            }                                                                  \
        }                                                                      \
        asm volatile("s_waitcnt lgkmcnt(0)\n\ts_barrier" ::: "memory");        \
    }

__global__ __launch_bounds__(512, 1) void k_fused(
        const unsigned short* __restrict__ xB,    // S frags
        const unsigned short* __restrict__ xG,    // G2 A frags
        const unsigned short* __restrict__ wF,    // W A-frags
        const float* __restrict__ bias,
        const float* __restrict__ invn,           // [B][N]
        float* __restrict__ out) {                // [B][C][N] f32
    int blk = blockIdx.x;
    // batch-affine XCD swizzle: XCD (blk&7) hosts batch (blk&7)>>1 only;
    // bijective over 256: blk = 8*(qt>>1) + 2*b + (qt&1)
    int b  = (blk & 7) >> 1;
    int qt = ((blk >> 3) << 1) | (blk & 1);       // 0..63
    int n0 = qt << 6;                             // 64 queries per block
    int t  = threadIdx.x;
    int wv = t >> 6, lane = t & 63;
    int l15 = lane & 15, q = lane >> 4;
    int ms = wv & 3;
    int np = wv >> 2;                // nq pair {2np, 2np+1}

    __shared__ unsigned short pbuf[2][64 * 72];   // [parity][nq row][72 m]
    __shared__ unsigned short zbuf[64 * 264];     // dedicated
    __shared__ float spbuf2[4][64];               // colsum partials [ms][nq]

    const unsigned short* xBb = xB + (size_t)b * 256 * 8 * 512;
    const unsigned short* xGb = xG + (size_t)b * 64 * 16 * 1024;
    const float* invb = invn + b * NN;

    // persistent Xq frags (B operand of transposed S)
    short8 aq[2][8];
    #pragma unroll
    for (int s = 0; s < 2; ++s)
        #pragma unroll
        for (int kk = 0; kk < 8; ++kk)
            aq[s][kk] = *(const short8*)(xBb
                + ((size_t)((n0 >> 4) + 2 * np + s) * 8 + kk) * 512 + lane * 8);
    float invq[2];
    #pragma unroll
    for (int s = 0; s < 2; ++s) invq[s] = invb[n0 + 16 * (2 * np + s) + l15];

    floatx4 zero4 = {0.f, 0.f, 0.f, 0.f};
    floatx4 Zacc[2][4];              // [ci: cct=wv+8ci][nqs]
    #pragma unroll
    for (int ci = 0; ci < 2; ++ci)
        #pragma unroll
        for (int nqs = 0; nqs < 4; ++nqs) Zacc[ci][nqs] = zero4;
    float csum[2] = {0.f, 0.f};

    // hot-loop pointers (constant strides)
    const unsigned short* bqp   = xBb + ms * 4096 + lane * 8;      // tile 0
    const unsigned short* xgp   = xGb + wv * 1024 + lane * 8;      // xg(0)
    const float*          invmp = invb + 16 * ms + 4 * q;          // m-tile 0

    short8 bqA[8], bqB[8];
    short8 xgA[2][2], xgB[2][2];
    #pragma unroll
    for (int kk = 0; kk < 8; ++kk)
        bqA[kk] = *(const short8*)(bqp + kk * 512);
    bqp += 16384;

    // peel it=0 (no G2 yet); loads xg(0) into xgA
    FUSED_STEP(0, bqA, bqB, xgB, xgA, false)
    // pairs it = 1..62
    for (int it2 = 0; it2 < 31; ++it2) {
        int itO = 2 * it2 + 1;
        FUSED_STEP(itO, bqB, bqA, xgA, xgB, true)
        int itE = 2 * it2 + 2;
        FUSED_STEP(itE, bqA, bqB, xgB, xgA, true)
    }
    // it = 63
    FUSED_STEP(63, bqB, bqA, xgA, xgB, true)
    // final G2(63): pbuf[1] x xgB
    {
        const unsigned short* pbR = pbuf[1];
        #pragma unroll
        for (int kk2 = 0; kk2 < 2; ++kk2)
            #pragma unroll
            for (int nqs = 0; nqs < 4; ++nqs) {
                short8 pbf = *(const short8*)(pbR + (16 * nqs + l15) * 72
                                              + kk2 * 32 + q * 8);
                Zacc[0][nqs] = mfma16(xgB[0][kk2], pbf, Zacc[0][nqs]);
                Zacc[1][nqs] = mfma16(xgB[1][kk2], pbf, Zacc[1][nqs]);
            }
    }

    // ---- colsum reduce over q-groups (lanes ^16, ^32) ----
    #pragma unroll
    for (int s = 0; s < 2; ++s) {
        csum[s] += __shfl_xor(csum[s], 16, 64);
        csum[s] += __shfl_xor(csum[s], 32, 64);
    }

    __syncthreads();
    // Z -> zbuf (scalar stores, dedicated LDS)
    #pragma unroll
    for (int ci = 0; ci < 2; ++ci) {
        int cct = wv + 8 * ci;
        #pragma unroll
        for (int nqs = 0; nqs < 4; ++nqs)
            #pragma unroll
            for (int i = 0; i < 4; ++i)
                zbuf[(16 * nqs + l15) * 264 + 16 * cct + 4 * q + i] = f2bf(Zacc[ci][nqs][i]);
    }
    if (q == 0) {
        #pragma unroll
        for (int s = 0; s < 2; ++s)
            spbuf2[ms][16 * (2 * np + s) + l15] = csum[s];
    }
    __syncthreads();

    float svals[4];
    #pragma unroll
    for (int nqs = 0; nqs < 4; ++nqs)
        svals[nqs] = spbuf2[0][16 * nqs + l15] + spbuf2[1][16 * nqs + l15]
                   + spbuf2[2][16 * nqs + l15] + spbuf2[3][16 * nqs + l15];

    // O = W*Z + b*svals
    float* ob = out + (size_t)b * CC * NN;
    floatx4 oa[2][4];
    #pragma unroll
    for (int ci = 0; ci < 2; ++ci) {
        int ct = wv + 8 * ci;
        floatx4 bv = *(const floatx4*)(bias + 16 * ct + 4 * q);
        #pragma unroll
        for (int nqs = 0; nqs < 4; ++nqs)
            #pragma unroll
            for (int i = 0; i < 4; ++i) oa[ci][nqs][i] = bv[i] * svals[nqs];
    }
    #pragma unroll
    for (int kk = 0; kk < 8; ++kk) {
        short8 wf0 = *(const short8*)(wF + (size_t)(wv * 8 + kk) * 512 + lane * 8);
        short8 wf1 = *(const short8*)(wF + (size_t)((wv + 8) * 8 + kk) * 512 + lane * 8);
        #pragma unroll
        for (int nqs = 0; nqs < 4; ++nqs) {
            short8 zf = *(const short8*)(&zbuf[(16 * nqs + l15) * 264 + 32 * kk + 8 * q]);
            oa[0][nqs] = mfma16(wf0, zf, oa[0][nqs]);
            oa[1][nqs] = mfma16(wf1, zf, oa[1][nqs]);
        }
    }
    #pragma unroll
    for (int ci = 0; ci < 2; ++ci) {
        int ct = wv + 8 * ci;
        #pragma unroll
        for (int nqs = 0; nqs < 4; ++nqs)
            #pragma unroll
            for (int i = 0; i < 4; ++i)
                ob[(size_t)(16 * ct + 4 * q + i) * NN + n0 + 16 * nqs + l15] = oa[ci][nqs][i];
    }
}

// ---------------------------------------------------------------------------
extern "C" void kernel_launch(void* const* d_in, const int* in_sizes, int n_in,
                              void* d_out, int out_size, void* d_ws, size_t ws_size,
                              hipStream_t stream) {
    const float* x    = (const float*)d_in[0];   // [4,256,64,64]
    const float* Wm   = (const float*)d_in[1];   // [256,256]
    const float* bias = (const float*)d_in[2];   // [256]
    float* out = (float*)d_out;

    // ws: psum 256KB | invn 64KB | xB 8MB | xG 8MB | wF 128KB  (~16.8MB)
    char* ws = (char*)d_ws;
    float* psum         = (float*)ws;
    float* invn         = (float*)(ws + 262144);
    unsigned short* xB  = (unsigned short*)(ws + 262144 + 65536);
    unsigned short* xG  = (unsigned short*)(ws + 262144 + 65536 + 8388608);
    unsigned short* wF  = (unsigned short*)(ws + 262144 + 65536 + 2 * 8388608);

    k_trans   <<<1024, 256, 0, stream>>>(x, xB, xG, psum);
    k_invwcast<<<96,   256, 0, stream>>>(psum, invn, Wm, wF);
    k_fused   <<<256,  512, 0, stream>>>(xB, xG, wF, bias, invn, out);
}

// Round 9
// 157.807 us; speedup vs baseline: 2.3015x; 1.0414x over previous
//
#include <hip/hip_runtime.h>
#include <stdint.h>

#define CC 256
#define NN 4096   // H*W = 64*64

typedef __attribute__((ext_vector_type(8))) short short8;
typedef __attribute__((ext_vector_type(4))) float floatx4;
typedef __attribute__((ext_vector_type(4))) unsigned int uint4v;
typedef __attribute__((ext_vector_type(2))) unsigned int uint2v;

__device__ __forceinline__ unsigned short f2bf(float f) {
    unsigned int u = __builtin_bit_cast(unsigned int, f);
    u = (u + 0x7FFFu + ((u >> 16) & 1u)) >> 16;   // RNE
    return (unsigned short)u;
}

// round-half-up pack of two floats to packed bf16x2 (2 VALU ops + perm);
// same rounding the pbuf path has used (validated) since round 0.
__device__ __forceinline__ unsigned int pack2bf(float lo, float hi) {
    return __byte_perm(__builtin_bit_cast(unsigned int, lo) + 0x8000u,
                       __builtin_bit_cast(unsigned int, hi) + 0x8000u, 0x7632);
}

__device__ __forceinline__ floatx4 mfma16(short8 a, short8 b, floatx4 c) {
    return __builtin_amdgcn_mfma_f32_16x16x32_bf16(a, b, c, 0, 0, 0);
}

// ---------------------------------------------------------------------------
// Fragment layouts (16x16x32 bf16; A-frag == B-frag lane map:
//   element(row = 16*tile + (lane&15), k = 32*kk + (lane>>4)*8 + j)):
// xB[b][nt 256][kk 8][lane][j] : row = n (pixel), k = c   (S operands)
// xG[b][mt 64][cct 16][kk2 2][lane][j] : row = c, k = m   (G2 A-operand)
// wF[ct 16][kk 8][lane][j]     : row = out-c, k = in-c    (epilogue A)
// ---------------------------------------------------------------------------

// ---------------------------------------------------------------------------
// k_trans v16: x -> xB + xG + psum, with (a) cheap pack2bf converts (was
// 4-op RNE f2bf x32/thread), (b) the W-cast of old k_invwcast folded in as
// 32 tail blocks (blk >= 1024) — saves a kernel launch.
// ---------------------------------------------------------------------------
__global__ __launch_bounds__(256) void k_trans(const float* __restrict__ x,
                                               unsigned short* __restrict__ xB,
                                               unsigned short* __restrict__ xG,
                                               float* __restrict__ psum,
                                               const float* __restrict__ Wm,
                                               unsigned short* __restrict__ wF) {
    int blk = blockIdx.x;
    int t = threadIdx.x;
    if (blk >= 1024) {
        // ---- W-cast tail (old k_invwcast else-branch) ----
        int idx = (blk - 1024) * 256 + t;        // 0..8191
        int f = idx >> 6, lane = idx & 63;
        int ct = f >> 3, kk = f & 7;
        int l15 = lane & 15, q = lane >> 4;
        const float* src = Wm + (size_t)(16 * ct + l15) * CC + 32 * kk + 8 * q;
        floatx4 a = *(const floatx4*)src;
        floatx4 c = *(const floatx4*)(src + 4);
        uint4v p = {pack2bf(a[0], a[1]), pack2bf(a[2], a[3]),
                    pack2bf(c[0], c[1]), pack2bf(c[2], c[3])};
        *(uint4v*)(wF + (size_t)f * 512 + lane * 8) = p;
        return;
    }
    int b  = blk >> 8;
    int cc = (blk >> 6) & 3;
    int nc = blk & 63;
    int c0 = cc << 6, n0 = nc << 6;
    __shared__ float tile[64][65];
    __shared__ float red[4][64];
    {
        int c   = t >> 2;
        int nn4 = (t & 3) << 4;
        const float* src = x + (size_t)(b * CC + c0 + c) * NN + n0 + nn4;
        #pragma unroll
        for (int j = 0; j < 16; j += 4) {
            floatx4 v = *(const floatx4*)(src + j);
            tile[c][nn4 + j + 0] = v[0];
            tile[c][nn4 + j + 1] = v[1];
            tile[c][nn4 + j + 2] = v[2];
            tile[c][nn4 + j + 3] = v[3];
        }
    }
    __syncthreads();
    int g = t >> 6, lane = t & 63, l15 = lane & 15, q = lane >> 4;
    #pragma unroll
    for (int kkl = 0; kkl < 2; ++kkl) {
        unsigned int w[4];
        #pragma unroll
        for (int j = 0; j < 4; ++j)
            w[j] = pack2bf(tile[32 * kkl + 8 * q + 2 * j][16 * g + l15],
                           tile[32 * kkl + 8 * q + 2 * j + 1][16 * g + l15]);
        uint4v p = {w[0], w[1], w[2], w[3]};
        *(uint4v*)(xB + ((size_t)(b * 256 + (n0 >> 4) + g) * 8 + (c0 >> 5) + kkl) * 512
                   + lane * 8) = p;
    }
    #pragma unroll
    for (int kk2 = 0; kk2 < 2; ++kk2) {
        unsigned int w[4];
        #pragma unroll
        for (int j = 0; j < 4; ++j)
            w[j] = pack2bf(tile[16 * g + l15][32 * kk2 + 8 * q + 2 * j],
                           tile[16 * g + l15][32 * kk2 + 8 * q + 2 * j + 1]);
        uint4v p = {w[0], w[1], w[2], w[3]};
        *(uint4v*)(xG + (size_t)(b * 64 + nc) * 16 * 1024
                   + ((size_t)((c0 >> 4) + g)) * 1024 + kk2 * 512 + lane * 8) = p;
    }
    {
        int n  = t & 63;
        int cq = t >> 6;
        float ss = 0.f;
        #pragma unroll
        for (int i = 0; i < 16; ++i) {
            float v = tile[cq * 16 + i][n];
            ss = fmaf(v, v, ss);
        }
        red[cq][n] = ss;
    }
    __syncthreads();
    if (t < 64) {
        float s = red[0][t] + red[1][t] + red[2][t] + red[3][t];
        psum[((size_t)(b * 64 + nc) * 64 + t) * 4 + cc] = s;
    }
}

// ---------------------------------------------------------------------------
// k_fused v16: round-0 v9 frame/step-order/registers VERBATIM (94.7us,
// VGPR 112), plus exactly two register-neutral deltas:
//  (1) batch-affine XCD swizzle (isolated test on the proven frame),
//  (2) inv-norms computed in a prologue from psum into LDS (invl[4096],
//      16KB) — replaces the invn global buffer and kills the k_invwcast
//      launch. invq/invm4 read from LDS; step macro otherwise unchanged
//      (G2 first, then S — the proven register-friendly order).
// ---------------------------------------------------------------------------
#define FUSED_STEP(IT, BQC, BQN, XGP, XGC, DO_G2)                              \
    {                                                                          \
        /* issue next key tile + this step's xg (consumed next step) */        \
        _Pragma("unroll")                                                      \
        for (int kk = 0; kk < 8; ++kk)                                         \
            BQN[kk] = *(const short8*)(bqp + kk * 512);                        \
        bqp += 16384;                                                          \
        _Pragma("unroll")                                                      \
        for (int ci = 0; ci < 2; ++ci)                                         \
            _Pragma("unroll")                                                  \
            for (int kk2 = 0; kk2 < 2; ++kk2)                                  \
                XGC[ci][kk2] = *(const short8*)(xgp + ci * 8192 + kk2 * 512);  \
        xgp += 16384;                                                          \
        floatx4 invm4 = *(const floatx4*)invmp;                                \
        invmp += 64;                                                           \
        /* G2(IT-1): pbuf[(IT-1)&1] x prev xg */                               \
        if (DO_G2) {                                                           \
            const unsigned short* pbR = pbuf[((IT) - 1) & 1];                  \
            _Pragma("unroll")                                                  \
            for (int kk2 = 0; kk2 < 2; ++kk2)                                  \
                _Pragma("unroll")                                              \
                for (int nqs = 0; nqs < 4; ++nqs) {                            \
                    short8 pbf = *(const short8*)(pbR + (16 * nqs + l15) * 72  \
                                                  + kk2 * 32 + q * 8);         \
                    Zacc[0][nqs] = mfma16(XGP[0][kk2], pbf, Zacc[0][nqs]);     \
                    Zacc[1][nqs] = mfma16(XGP[1][kk2], pbf, Zacc[1][nqs]);     \
                }                                                              \
        }                                                                      \
        /* S(IT) transposed: A=keys, B=queries -> D rows = m-local */          \
        floatx4 s0a = zero4, s0b = zero4, s1a = zero4, s1b = zero4;            \
        _Pragma("unroll")                                                      \
        for (int kk = 0; kk < 8; kk += 2) {                                    \
            s0a = mfma16(BQC[kk],     aq[0][kk],     s0a);                     \
            s1a = mfma16(BQC[kk],     aq[1][kk],     s1a);                     \
            s0b = mfma16(BQC[kk + 1], aq[0][kk + 1], s0b);                     \
            s1b = mfma16(BQC[kk + 1], aq[1][kk + 1], s1b);                     \
        }                                                                      \
        /* P(IT) = relu(S*inv)^2 -> packed b64 -> pbuf[IT&1]; csum */          \
        {                                                                      \
            unsigned short* pbW = pbuf[(IT) & 1];                              \
            _Pragma("unroll")                                                  \
            for (int s = 0; s < 2; ++s) {                                      \
                floatx4 sv = (s == 0) ? (s0a + s0b) : (s1a + s1b);             \
                unsigned int pk0, pk1;                                         \
                float v0 = sv[0] * (invm4[0] * invq[s]);                       \
                float v1 = sv[1] * (invm4[1] * invq[s]);                       \
                float v2 = sv[2] * (invm4[2] * invq[s]);                       \
                float v3 = sv[3] * (invm4[3] * invq[s]);                       \
                v0 = fmaxf(v0, 0.f); v1 = fmaxf(v1, 0.f);                      \
                v2 = fmaxf(v2, 0.f); v3 = fmaxf(v3, 0.f);                      \
                v0 *= v0; v1 *= v1; v2 *= v2; v3 *= v3;                        \
                csum[s] += (v0 + v1) + (v2 + v3);                              \
                pk0 = __byte_perm(__builtin_bit_cast(unsigned int, v0) + 0x8000u, \
                                  __builtin_bit_cast(unsigned int, v1) + 0x8000u, \
                                  0x7632);                                     \
                pk1 = __byte_perm(__builtin_bit_cast(unsigned int, v2) + 0x8000u, \
                                  __builtin_bit_cast(unsigned int, v3) + 0x8000u, \
                                  0x7632);                                     \
                uint2v w2 = {pk0, pk1};                                        \
                *(uint2v*)(pbW + (16 * (2 * np + s) + l15) * 72                \
                           + 16 * ms + 4 * q) = w2;                            \
            }                                                                  \
        }                                                                      \
        asm volatile("s_waitcnt lgkmcnt(0)\n\ts_barrier" ::: "memory");        \
    }

__global__ __launch_bounds__(512, 1) void k_fused(
        const unsigned short* __restrict__ xB,    // S frags
        const unsigned short* __restrict__ xG,    // G2 A frags
        const unsigned short* __restrict__ wF,    // W A-frags
        const float* __restrict__ bias,
        const float* __restrict__ psum,           // [B][N][4] partial norms
        float* __restrict__ out) {                // [B][C][N] f32
    int blk = blockIdx.x;
    // batch-affine XCD swizzle: XCD (blk&7) hosts batch (blk&7)>>1 only;
    // bijective over 256: blk = 8*(qt>>1) + 2*b + (qt&1)
    int b  = (blk & 7) >> 1;
    int qt = ((blk >> 3) << 1) | (blk & 1);       // 0..63
    int n0 = qt << 6;                             // 64 queries per block
    int t  = threadIdx.x;
    int wv = t >> 6, lane = t & 63;
    int l15 = lane & 15, q = lane >> 4;
    int ms = wv & 3;
    int np = wv >> 2;                // nq pair {2np, 2np+1}

    __shared__ unsigned short pbuf[2][64 * 72];   // [parity][nq row][72 m]
    __shared__ unsigned short zbuf[64 * 264];     // dedicated
    __shared__ float spbuf2[4][64];               // colsum partials [ms][nq]
    __shared__ float invl[4096];                  // inv-norms, batch b (16KB)

    const unsigned short* xBb = xB + (size_t)b * 256 * 8 * 512;
    const unsigned short* xGb = xG + (size_t)b * 64 * 16 * 1024;

    // ---- prologue: invl[p] = 1/max(sqrt(sum psum), eps) for all 4096 ----
    {
        const float* pb = psum + (size_t)b * NN * 4;
        #pragma unroll
        for (int i = 0; i < 8; ++i) {
            int p = t + i * 512;
            floatx4 ps = *(const floatx4*)(pb + (size_t)p * 4);
            float ss = (ps[0] + ps[1]) + (ps[2] + ps[3]);
            invl[p] = 1.f / fmaxf(sqrtf(ss), 1e-8f);
        }
    }

    // persistent Xq frags (B operand of transposed S)
    short8 aq[2][8];
    #pragma unroll
    for (int s = 0; s < 2; ++s)
        #pragma unroll
        for (int kk = 0; kk < 8; ++kk)
            aq[s][kk] = *(const short8*)(xBb
                + ((size_t)((n0 >> 4) + 2 * np + s) * 8 + kk) * 512 + lane * 8);

    floatx4 zero4 = {0.f, 0.f, 0.f, 0.f};
    floatx4 Zacc[2][4];              // [ci: cct=wv+8ci][nqs]
    #pragma unroll
    for (int ci = 0; ci < 2; ++ci)
        #pragma unroll
        for (int nqs = 0; nqs < 4; ++nqs) Zacc[ci][nqs] = zero4;
    float csum[2] = {0.f, 0.f};

    // hot-loop pointers (constant strides)
    const unsigned short* bqp   = xBb + ms * 4096 + lane * 8;      // tile 0
    const unsigned short* xgp   = xGb + wv * 1024 + lane * 8;      // xg(0)

    short8 bqA[8], bqB[8];
    short8 xgA[2][2], xgB[2][2];
    #pragma unroll
    for (int kk = 0; kk < 8; ++kk)
        bqA[kk] = *(const short8*)(bqp + kk * 512);
    bqp += 16384;

    __syncthreads();   // publish invl
    float invq[2];
    #pragma unroll
    for (int s = 0; s < 2; ++s) invq[s] = invl[n0 + 16 * (2 * np + s) + l15];
    const float* invmp = invl + 16 * ms + 4 * q;   // m-tile 0 (LDS walk)

    // peel it=0 (no G2 yet); loads xg(0) into xgA
    FUSED_STEP(0, bqA, bqB, xgB, xgA, false)
    // pairs it = 1..62
    for (int it2 = 0; it2 < 31; ++it2) {
        int itO = 2 * it2 + 1;
        FUSED_STEP(itO, bqB, bqA, xgA, xgB, true)
        int itE = 2 * it2 + 2;
        FUSED_STEP(itE, bqA, bqB, xgB, xgA, true)
    }
    // it = 63
    FUSED_STEP(63, bqB, bqA, xgA, xgB, true)
    // final G2(63): pbuf[1] x xgB
    {
        const unsigned short* pbR = pbuf[1];
        #pragma unroll
        for (int kk2 = 0; kk2 < 2; ++kk2)
            #pragma unroll
            for (int nqs = 0; nqs < 4; ++nqs) {
                short8 pbf = *(const short8*)(pbR + (16 * nqs + l15) * 72
                                              + kk2 * 32 + q * 8);
                Zacc[0][nqs] = mfma16(xgB[0][kk2], pbf, Zacc[0][nqs]);
                Zacc[1][nqs] = mfma16(xgB[1][kk2], pbf, Zacc[1][nqs]);
            }
    }

    // ---- colsum reduce over q-groups (lanes ^16, ^32) ----
    #pragma unroll
    for (int s = 0; s < 2; ++s) {
        csum[s] += __shfl_xor(csum[s], 16, 64);
        csum[s] += __shfl_xor(csum[s], 32, 64);
    }

    __syncthreads();
    // Z -> zbuf (scalar stores, dedicated LDS)
    #pragma unroll
    for (int ci = 0; ci < 2; ++ci) {
        int cct = wv + 8 * ci;
        #pragma unroll
        for (int nqs = 0; nqs < 4; ++nqs)
            #pragma unroll
            for (int i = 0; i < 4; ++i)
                zbuf[(16 * nqs + l15) * 264 + 16 * cct + 4 * q + i] = f2bf(Zacc[ci][nqs][i]);
    }
    if (q == 0) {
        #pragma unroll
        for (int s = 0; s < 2; ++s)
            spbuf2[ms][16 * (2 * np + s) + l15] = csum[s];
    }
    __syncthreads();

    float svals[4];
    #pragma unroll
    for (int nqs = 0; nqs < 4; ++nqs)
        svals[nqs] = spbuf2[0][16 * nqs + l15] + spbuf2[1][16 * nqs + l15]
                   + spbuf2[2][16 * nqs + l15] + spbuf2[3][16 * nqs + l15];

    // O = W*Z + b*svals
    float* ob = out + (size_t)b * CC * NN;
    floatx4 oa[2][4];
    #pragma unroll
    for (int ci = 0; ci < 2; ++ci) {
        int ct = wv + 8 * ci;
        floatx4 bv = *(const floatx4*)(bias + 16 * ct + 4 * q);
        #pragma unroll
        for (int nqs = 0; nqs < 4; ++nqs)
            #pragma unroll
            for (int i = 0; i < 4; ++i) oa[ci][nqs][i] = bv[i] * svals[nqs];
    }
    #pragma unroll
    for (int kk = 0; kk < 8; ++kk) {
        short8 wf0 = *(const short8*)(wF + (size_t)(wv * 8 + kk) * 512 + lane * 8);
        short8 wf1 = *(const short8*)(wF + (size_t)((wv + 8) * 8 + kk) * 512 + lane * 8);
        #pragma unroll
        for (int nqs = 0; nqs < 4; ++nqs) {
            short8 zf = *(const short8*)(&zbuf[(16 * nqs + l15) * 264 + 32 * kk + 8 * q]);
            oa[0][nqs] = mfma16(wf0, zf, oa[0][nqs]);
            oa[1][nqs] = mfma16(wf1, zf, oa[1][nqs]);
        }
    }
    #pragma unroll
    for (int ci = 0; ci < 2; ++ci) {
        int ct = wv + 8 * ci;
        #pragma unroll
        for (int nqs = 0; nqs < 4; ++nqs)
            #pragma unroll
            for (int i = 0; i < 4; ++i)
                ob[(size_t)(16 * ct + 4 * q + i) * NN + n0 + 16 * nqs + l15] = oa[ci][nqs][i];
    }
}

// ---------------------------------------------------------------------------
extern "C" void kernel_launch(void* const* d_in, const int* in_sizes, int n_in,
                              void* d_out, int out_size, void* d_ws, size_t ws_size,
                              hipStream_t stream) {
    const float* x    = (const float*)d_in[0];   // [4,256,64,64]
    const float* Wm   = (const float*)d_in[1];   // [256,256]
    const float* bias = (const float*)d_in[2];   // [256]
    float* out = (float*)d_out;

    // ws: psum 256KB | (unused 64KB) | xB 8MB | xG 8MB | wF 128KB  (~16.8MB)
    char* ws = (char*)d_ws;
    float* psum         = (float*)ws;
    unsigned short* xB  = (unsigned short*)(ws + 262144 + 65536);
    unsigned short* xG  = (unsigned short*)(ws + 262144 + 65536 + 8388608);
    unsigned short* wF  = (unsigned short*)(ws + 262144 + 65536 + 2 * 8388608);

    k_trans <<<1056, 256, 0, stream>>>(x, xB, xG, psum, Wm, wF);
    k_fused <<<256,  512, 0, stream>>>(xB, xG, wF, bias, psum, out);
}